// Round 1
// baseline (154.441 us; speedup 1.0000x reference)
//
#include <hip/hip_runtime.h>
#include <hip/hip_bf16.h>

#define NNODES   1024
#define NEDGES   4096
#define NFACT    64
#define NBATCH   256
#define NSRC     16
#define MAXNNZ   64   // capacity; actual nnz per row is 32 by construction
#define MAXITER  32   // scan length in the reference

// Kernel 1: per-factor sparse propagation.
// One wave (64 threads) per factor. v[1024] lives in LDS.
__global__ __launch_bounds__(64) void prop_kernel(
    const float* __restrict__ kern,      // [64, 4096]
    const int*   __restrict__ edges,     // [4096, 2] (col=src, row=dst)
    const int*   __restrict__ sources,   // [16]
    float*       __restrict__ W)         // [64, 1024] out (d_ws)
{
    __shared__ float v[NNODES];
    __shared__ float wbuf[MAXNNZ];
    __shared__ int   srcbuf[MAXNNZ];
    __shared__ int   dstbuf[MAXNNZ];
    __shared__ int   cnt;
    __shared__ float s_sum, s_c;

    const int f = blockIdx.x;
    const int t = threadIdx.x;  // 0..63

    if (t == 0) cnt = 0;
    __syncthreads();

    // Compact the nonzero entries of kernel row f into LDS edge list.
    for (int e = t; e < NEDGES; e += 64) {
        float kv = kern[f * NEDGES + e];
        if (kv != 0.0f) {
            int slot = atomicAdd(&cnt, 1);
            if (slot < MAXNNZ) {
                wbuf[slot]   = kv;
                srcbuf[slot] = edges[e * 2 + 0];
                dstbuf[slot] = edges[e * 2 + 1];
            }
        }
    }
    // Init v = source indicator.
    for (int n = t; n < NNODES; n += 64) v[n] = 0.0f;
    __syncthreads();
    if (t < NSRC) v[sources[t]] = 1.0f;
    __syncthreads();

    int nnz = cnt;
    if (nnz > MAXNNZ) nnz = MAXNNZ;
    int T = nnz < MAXITER ? nnz : MAXITER;   // iters[f] = count_nonzero, capped by scan length

    for (int it = 0; it < T; ++it) {
        // s = sum(v) — wave reduce over 16 elems/lane.
        float ps = 0.f;
        for (int n = t; n < NNODES; n += 64) ps += v[n];
        for (int off = 32; off >= 1; off >>= 1) ps += __shfl_down(ps, off);

        // Per-edge contribution c_e = w_e * v[src_e]; total over all nnz edges.
        float ce = 0.f;
        if (t < nnz) ce = wbuf[t] * v[srcbuf[t]];
        float tc = ce;
        for (int off = 32; off >= 1; off >>= 1) tc += __shfl_down(tc, off);

        if (t == 0) { s_sum = ps; s_c = tc; }
        __syncthreads();

        // New v is supported only on {0} ∪ {dst_e}. Zero, then scatter.
        for (int n = t; n < NNODES; n += 64) v[n] = 0.0f;
        __syncthreads();
        if (t == 0) v[0] = s_sum - s_c;                 // replaced row 0: s - colsum·v
        if (t < nnz) {
            int d = dstbuf[t];
            if (d != 0) atomicAdd(&v[d], ce);           // duplicate dst possible -> atomic
        }
        __syncthreads();
    }

    // W[f] = v - source_indicator  (sources are unique -> plain subtract)
    if (t < NSRC) v[sources[t]] -= 1.0f;
    __syncthreads();
    for (int n = t; n < NNODES; n += 64) W[f * NNODES + n] = v[n];
}

// Kernel 2: fused output GEMMs.
//   out[0 : 256*1024)          = x @ W       [256,64]@[64,1024]
//   out[256*1024 : +256*4096)  = x @ kernel  [256,64]@[64,4096]
__global__ __launch_bounds__(256) void out_kernel(
    const float* __restrict__ x,     // [256, 64]
    const float* __restrict__ W,     // [64, 1024]
    const float* __restrict__ kern,  // [64, 4096]
    float*       __restrict__ out)
{
    const int NP = NBATCH * NNODES;   // 262144
    const int NR = NBATCH * NEDGES;   // 1048576
    int idx = blockIdx.x * blockDim.x + threadIdx.x;
    if (idx < NP) {
        int b = idx >> 10;            // / 1024
        int n = idx & 1023;
        float acc = 0.f;
        #pragma unroll
        for (int k = 0; k < NFACT; ++k) acc += x[b * NFACT + k] * W[k * NNODES + n];
        out[idx] = acc;
    } else if (idx < NP + NR) {
        int j = idx - NP;
        int b = j >> 12;              // / 4096
        int e = j & 4095;
        float acc = 0.f;
        #pragma unroll
        for (int k = 0; k < NFACT; ++k) acc += x[b * NFACT + k] * kern[k * NEDGES + e];
        out[NP + j] = acc;
    }
}

extern "C" void kernel_launch(void* const* d_in, const int* in_sizes, int n_in,
                              void* d_out, int out_size, void* d_ws, size_t ws_size,
                              hipStream_t stream) {
    const float* x       = (const float*)d_in[0];
    const float* kern    = (const float*)d_in[1];
    const int*   edges   = (const int*)d_in[2];
    const int*   sources = (const int*)d_in[3];
    float* out = (float*)d_out;
    float* W   = (float*)d_ws;   // 64*1024 floats = 256 KB scratch

    prop_kernel<<<NFACT, 64, 0, stream>>>(kern, edges, sources, W);

    const int total = NBATCH * NNODES + NBATCH * NEDGES;  // 1310720
    out_kernel<<<(total + 255) / 256, 256, 0, stream>>>(x, W, kern, out);
}

// Round 3
// 96.798 us; speedup vs baseline: 1.5955x; 1.5955x over previous
//
#include <hip/hip_runtime.h>
#include <hip/hip_bf16.h>

#define NNODES   1024
#define NEDGES   4096
#define NFACT    64
#define NBATCH   256
#define NSRC     16
#define MAXNNZ   64   // capacity; actual nnz per row is 32 by construction
#define MAXITER  32   // scan length in the reference

// Kernel 1: per-factor sparse propagation with COMPACT state.
// One wave (64 threads) per factor. State: S = sum(v) (uniform), val_e = v[src_e] (lane e).
// v is only supported on {0} ∪ {dst_e}, so never materialize the 1024-vector in the loop.
__global__ __launch_bounds__(64) void prop_kernel(
    const float* __restrict__ kern,      // [64, 4096]
    const int*   __restrict__ edges,     // [4096, 2] (col=src, row=dst)
    const int*   __restrict__ sources,   // [16]
    float*       __restrict__ W)         // [64, 1024] out (d_ws)
{
    __shared__ float v_lds[NNODES];      // used only for the final W-row write
    __shared__ float wbuf[MAXNNZ];
    __shared__ int   srcbuf[MAXNNZ];
    __shared__ int   dstbuf[MAXNNZ];
    __shared__ float c_lds[MAXNNZ];
    __shared__ int   cnt;

    const int f = blockIdx.x;
    const int t = threadIdx.x;  // 0..63 (single wave)

    if (t == 0) cnt = 0;
    __syncthreads();

    // Compact the nonzero entries of kernel row f into an LDS edge list (float4 scan).
    const float4* kern4 = (const float4*)kern;
    for (int i = 0; i < NEDGES / 4 / 64; ++i) {          // 16 iters
        int e4 = t + i * 64;
        float4 kv = kern4[f * (NEDGES / 4) + e4];
        float vals[4] = {kv.x, kv.y, kv.z, kv.w};
        #pragma unroll
        for (int c = 0; c < 4; ++c) {
            if (vals[c] != 0.0f) {
                int e = e4 * 4 + c;
                int slot = atomicAdd(&cnt, 1);
                if (slot < MAXNNZ) {
                    wbuf[slot]   = vals[c];
                    srcbuf[slot] = edges[e * 2 + 0];
                    dstbuf[slot] = edges[e * 2 + 1];
                }
            }
        }
    }
    __syncthreads();

    int nnz = cnt;
    if (nnz > MAXNNZ) nnz = MAXNNZ;
    const int T = nnz < MAXITER ? nnz : MAXITER;

    // Per-lane edge data
    const bool active = (t < nnz);
    const float w_e  = active ? wbuf[t]   : 0.0f;
    const int   src  = active ? srcbuf[t] : -1;
    const int   dst  = active ? dstbuf[t] : -1;

    // Gather mask: bit e' set iff dst[e'] == src  (expected ~1 bit)
    unsigned long long gmask = 0ull;
    for (int e2 = 0; e2 < nnz; ++e2) {
        if (dstbuf[e2] == src) gmask |= (1ull << e2);
    }

    // Initial state: v = indicator(sources); S = NSRC; val_e = (src in sources)
    float S = (float)NSRC;
    float val = 0.0f;
    #pragma unroll
    for (int s = 0; s < NSRC; ++s) {
        if (sources[s] == src) val = 1.0f;
    }

    float c_last = 0.0f, v0_last = 0.0f;

    for (int it = 0; it < T; ++it) {
        float c = w_e * val;
        c_lds[t] = c;                       // single wave: no barrier needed, waitcnt suffices

        // Two interleaved 5-step xor reduces over lanes 0..31 (ILP=2)
        float a = c;
        float b = (dst == 0) ? c : 0.0f;
        #pragma unroll
        for (int o = 16; o >= 1; o >>= 1) {
            a += __shfl_xor(a, o);
            b += __shfl_xor(b, o);
        }
        float C = a, C0 = b;

        float v0 = S - C;                   // new v[0] (row-0 replacement)
        S = S - C0;                         // new sum(v)

        // new val_e = v'[src_e]
        float nv = 0.0f;
        unsigned long long m = gmask;
        while (m) {
            int i = __ffsll(m) - 1;
            nv += c_lds[i];
            m &= m - 1;
        }
        val = (src == 0) ? v0 : nv;

        c_last = c; v0_last = v0;
    }

    // Materialize W[f] = v_final - indicator(sources)
    for (int n = t; n < NNODES; n += 64) v_lds[n] = 0.0f;
    __syncthreads();
    if (T > 0) {
        if (t == 0) v_lds[0] = v0_last;
        if (active && dst != 0) atomicAdd(&v_lds[dst], c_last);
    } else {
        if (t < NSRC) v_lds[sources[t]] = 1.0f;
    }
    __syncthreads();
    if (t < NSRC) atomicAdd(&v_lds[sources[t]], -1.0f);
    __syncthreads();

    float4* Wrow4 = (float4*)(W + f * NNODES);
    const float4* v4 = (const float4*)v_lds;
    #pragma unroll
    for (int i = 0; i < NNODES / 4 / 64; ++i)            // 4 iters
        Wrow4[t + i * 64] = v4[t + i * 64];
}

// Kernel 2: fused output GEMMs, float4 per thread.
//   out[0 : 256*1024)          = x @ W       [256,64]@[64,1024]
//   out[256*1024 : +256*4096)  = x @ kernel  [256,64]@[64,4096]
__global__ __launch_bounds__(256) void out_kernel(
    const float* __restrict__ x,     // [256, 64]
    const float* __restrict__ W,     // [64, 1024]
    const float* __restrict__ kern,  // [64, 4096]
    float*       __restrict__ out)
{
    const int NP4 = NBATCH * NNODES / 4;   // 65536
    const int NR4 = NBATCH * NEDGES / 4;   // 262144
    int idx = blockIdx.x * blockDim.x + threadIdx.x;
    float4* out4 = (float4*)out;

    if (idx < NP4) {
        int b  = idx >> 8;                  // 256 col-groups per row
        int n4 = idx & 255;
        const float4* Wv = (const float4*)W;
        float4 acc = {0.f, 0.f, 0.f, 0.f};
        #pragma unroll
        for (int k = 0; k < NFACT; ++k) {
            float xv = x[b * NFACT + k];
            float4 wv = Wv[k * 256 + n4];
            acc.x += xv * wv.x; acc.y += xv * wv.y;
            acc.z += xv * wv.z; acc.w += xv * wv.w;
        }
        out4[idx] = acc;
    } else if (idx < NP4 + NR4) {
        int j  = idx - NP4;
        int b  = j >> 10;                   // 1024 col-groups per row
        int e4 = j & 1023;
        const float4* Kv = (const float4*)kern;
        float4 acc = {0.f, 0.f, 0.f, 0.f};
        #pragma unroll
        for (int k = 0; k < NFACT; ++k) {
            float xv = x[b * NFACT + k];
            float4 kv = Kv[k * 1024 + e4];
            acc.x += xv * kv.x; acc.y += xv * kv.y;
            acc.z += xv * kv.z; acc.w += xv * kv.w;
        }
        out4[NP4 + j] = acc;
    }
}

extern "C" void kernel_launch(void* const* d_in, const int* in_sizes, int n_in,
                              void* d_out, int out_size, void* d_ws, size_t ws_size,
                              hipStream_t stream) {
    const float* x       = (const float*)d_in[0];
    const float* kern    = (const float*)d_in[1];
    const int*   edges   = (const int*)d_in[2];
    const int*   sources = (const int*)d_in[3];
    float* out = (float*)d_out;
    float* W   = (float*)d_ws;   // 64*1024 floats = 256 KB scratch

    prop_kernel<<<NFACT, 64, 0, stream>>>(kern, edges, sources, W);

    const int total4 = NBATCH * NNODES / 4 + NBATCH * NEDGES / 4;  // 327680
    out_kernel<<<(total4 + 255) / 256, 256, 0, stream>>>(x, W, kern, out);
}

// Round 4
// 83.106 us; speedup vs baseline: 1.8583x; 1.1647x over previous
//
#include <hip/hip_runtime.h>
#include <hip/hip_bf16.h>

#define NNODES   1024
#define NEDGES   4096
#define NFACT    64
#define NBATCH   256
#define NSRC     16
#define MAXNNZ   64   // capacity; actual nnz per row is 32 by construction
#define MAXITER  32   // scan length in the reference

#define RECON_BLOCKS 512   // 4 e4-tiles x 128 b-pairs
#define FLOWS_BLOCKS 128   // 128 b-pairs

// Kernel 1: 64 prop blocks (factor propagation -> W) + 512 recon blocks
// (out2 = x @ kernel), running concurrently. recon has no dependency on W.
__global__ __launch_bounds__(256) void k1(
    const float* __restrict__ kern,      // [64, 4096]
    const int*   __restrict__ edges,     // [4096, 2] (col=src, row=dst)
    const int*   __restrict__ sources,   // [16]
    const float* __restrict__ x,         // [256, 64]
    float*       __restrict__ W,         // [64, 1024] (d_ws)
    float*       __restrict__ out)       // [256*1024 | 256*4096]
{
    if (blockIdx.x >= NFACT) {
        // ---- recon: out[NP + b*4096 + e] = sum_k x[b][k] * kern[k][e] ----
        int r  = blockIdx.x - NFACT;          // 0..511
        int e4 = (r & 3) * 256 + threadIdx.x; // 0..1023 (float4 col)
        int b0 = (r >> 2) * 2;                // batch pair
        const float4* Kv  = (const float4*)kern;
        const float*  xr0 = x + b0 * NFACT;   // uniform rows -> s_load
        const float*  xr1 = xr0 + NFACT;
        float4 a0 = {0.f,0.f,0.f,0.f}, a1 = {0.f,0.f,0.f,0.f};
        #pragma unroll 4
        for (int k = 0; k < NFACT; ++k) {
            float4 kv = Kv[k * (NEDGES/4) + e4];
            float x0 = xr0[k], x1 = xr1[k];
            a0.x += x0*kv.x; a0.y += x0*kv.y; a0.z += x0*kv.z; a0.w += x0*kv.w;
            a1.x += x1*kv.x; a1.y += x1*kv.y; a1.z += x1*kv.z; a1.w += x1*kv.w;
        }
        float4* o4 = (float4*)(out + NBATCH * NNODES);
        o4[ b0      * (NEDGES/4) + e4] = a0;
        o4[(b0 + 1) * (NEDGES/4) + e4] = a1;
        return;
    }

    // ---- prop: compact-state propagation for factor f ----
    __shared__ float v_lds[NNODES];
    __shared__ float wbuf[MAXNNZ];
    __shared__ int   srcbuf[MAXNNZ];
    __shared__ int   dstbuf[MAXNNZ];
    __shared__ float c_lds[MAXNNZ];
    __shared__ int   cnt;

    const int f = blockIdx.x;
    const int t = threadIdx.x;   // 0..255

    if (t == 0) cnt = 0;
    __syncthreads();

    // Compact nnz of kernel row f (all 256 threads, float4 scan: 4 iters).
    const float4* kern4 = (const float4*)(kern + f * NEDGES);
    #pragma unroll
    for (int i = 0; i < NEDGES/4/256; ++i) {
        int e4 = t + i * 256;
        float4 kv = kern4[e4];
        float vals[4] = {kv.x, kv.y, kv.z, kv.w};
        #pragma unroll
        for (int c = 0; c < 4; ++c) {
            if (vals[c] != 0.f) {
                int slot = atomicAdd(&cnt, 1);
                if (slot < MAXNNZ) {
                    wbuf[slot]   = vals[c];
                    int e        = e4 * 4 + c;
                    srcbuf[slot] = edges[2*e];
                    dstbuf[slot] = edges[2*e + 1];
                }
            }
        }
    }
    __syncthreads();

    const int nnz = min(cnt, MAXNNZ);
    const int T   = min(nnz, MAXITER);

    for (int n = t; n < NNODES; n += 256) v_lds[n] = 0.f;
    __syncthreads();

    if (t < 64) {   // wave 0 only; no barriers inside
        const bool  active = (t < nnz);
        const float w_e = active ? wbuf[t]   : 0.f;
        const int   src = active ? srcbuf[t] : -1;
        const int   dst = active ? dstbuf[t] : -1;

        // gather mask: bit e' iff dst[e'] == src
        unsigned long long gmask = 0ull;
        for (int e2 = 0; e2 < nnz; ++e2)
            if (dstbuf[e2] == src) gmask |= (1ull << e2);

        float val = 0.f;
        for (int s = 0; s < NSRC; ++s)
            if (sources[s] == src) val = 1.f;
        float S = (float)NSRC;

        // turbo eligibility: no src==0 edge, no dst==0 edge, no duplicate dst
        unsigned long long anybad =
            __ballot(active && (src == 0 || dst == 0)) |
            __ballot(__popcll(gmask) > 1);

        if (T > 0) {
            float c_fin = 0.f, v0_fin = 0.f;
            if (anybad == 0ull) {
                // ---- turbo: val' = c from (unique) edge with dst == src ----
                const int   gidx = gmask ? (__ffsll(gmask) - 1) : t;
                const float gsel = gmask ? 1.f : 0.f;
                float c = 0.f;
                for (int it = 0; it < T; ++it) {
                    c = w_e * val;
                    float g = __shfl(c, gidx);
                    val = gsel * g;
                }
                float a = c;                       // one final reduce for v0
                #pragma unroll
                for (int o = 32; o >= 1; o >>= 1) a += __shfl_xor(a, o);
                c_fin = c; v0_fin = S - a;
            } else {
                // ---- general path ----
                float c = 0.f, v0 = 0.f;
                for (int it = 0; it < T; ++it) {
                    c = w_e * val;
                    c_lds[t] = c;
                    float a = c;
                    float b = (dst == 0) ? c : 0.f;
                    #pragma unroll
                    for (int o = 32; o >= 1; o >>= 1) {
                        a += __shfl_xor(a, o);
                        b += __shfl_xor(b, o);
                    }
                    v0 = S - a;      // new v[0] (row-0 replacement)
                    S  = S - b;      // new sum(v)
                    float nv = 0.f;
                    unsigned long long m = gmask;
                    while (m) { int i = __ffsll(m) - 1; nv += c_lds[i]; m &= m - 1; }
                    val = (src == 0) ? v0 : nv;
                }
                c_fin = c; v0_fin = v0;
            }
            if (t == 0) v_lds[0] = v0_fin;
            if (active && dst != 0) atomicAdd(&v_lds[dst], c_fin);
        } else {
            if (t < NSRC) v_lds[sources[t]] = 1.f;
        }
    }
    __syncthreads();
    if (t < NSRC) atomicAdd(&v_lds[sources[t]], -1.f);
    __syncthreads();

    // W[f] = v  (256 threads x 1 float4)
    float4* Wr = (float4*)(W + f * NNODES);
    const float4* v4 = (const float4*)v_lds;
    Wr[t] = v4[t];
}

// Kernel 2: flows = x @ W  [256,64]@[64,1024] -> out[0 : 256*1024)
__global__ __launch_bounds__(256) void k2(
    const float* __restrict__ x,     // [256, 64]
    const float* __restrict__ W,     // [64, 1024]
    float*       __restrict__ out)
{
    const int b0 = blockIdx.x * 2;
    const int t  = threadIdx.x;      // float4 col 0..255
    const float4* Wv  = (const float4*)W;
    const float*  xr0 = x + b0 * NFACT;   // uniform -> s_load
    const float*  xr1 = xr0 + NFACT;
    float4 a0 = {0.f,0.f,0.f,0.f}, a1 = {0.f,0.f,0.f,0.f};
    #pragma unroll 4
    for (int k = 0; k < NFACT; ++k) {
        float4 wv = Wv[k * (NNODES/4) + t];
        float x0 = xr0[k], x1 = xr1[k];
        a0.x += x0*wv.x; a0.y += x0*wv.y; a0.z += x0*wv.z; a0.w += x0*wv.w;
        a1.x += x1*wv.x; a1.y += x1*wv.y; a1.z += x1*wv.z; a1.w += x1*wv.w;
    }
    float4* o4 = (float4*)out;
    o4[ b0      * (NNODES/4) + t] = a0;
    o4[(b0 + 1) * (NNODES/4) + t] = a1;
}

extern "C" void kernel_launch(void* const* d_in, const int* in_sizes, int n_in,
                              void* d_out, int out_size, void* d_ws, size_t ws_size,
                              hipStream_t stream) {
    const float* x       = (const float*)d_in[0];
    const float* kern    = (const float*)d_in[1];
    const int*   edges   = (const int*)d_in[2];
    const int*   sources = (const int*)d_in[3];
    float* out = (float*)d_out;
    float* W   = (float*)d_ws;   // 64*1024 floats = 256 KB scratch

    k1<<<NFACT + RECON_BLOCKS, 256, 0, stream>>>(kern, edges, sources, x, W, out);
    k2<<<FLOWS_BLOCKS, 256, 0, stream>>>(x, W, out);
}